// Round 2
// baseline (477.975 us; speedup 1.0000x reference)
//
#include <hip/hip_runtime.h>
#include <stdint.h>

#define N_K   10000
#define CIN   3
#define SEQ   1000
#define KM    11
#define NBUCKET 1024

#define NB    2        // batches per block
#define NJJ   64       // kernels per block
#define XSLOT 1004     // u64 slots per parity copy (2 zero + 1000 data + 2 zero)
#define XSTR  (2*XSLOT)

typedef _Float16 h2 __attribute__((ext_vector_type(2)));

// ---------------- counting sort of kernel indices by out_len (descending) ----
__global__ __launch_bounds__(1024) void sort_kernel(const int* __restrict__ out_len,
                                                    int* __restrict__ sorted_idx) {
    __shared__ int ha[NBUCKET];
    __shared__ int hb[NBUCKET];
    const int tid = threadIdx.x;
    ha[tid] = 0;
    __syncthreads();
    for (int jx = tid; jx < N_K; jx += 1024) {
        int key = (NBUCKET - 1) - min(out_len[jx], NBUCKET - 1);  // descending
        atomicAdd(&ha[key], 1);
    }
    __syncthreads();
    int* cur = ha;
    int* oth = hb;
    for (int off = 1; off < NBUCKET; off <<= 1) {
        int v = cur[tid];
        if (tid >= off) v += cur[tid - off];
        oth[tid] = v;
        __syncthreads();
        int* tp = cur; cur = oth; oth = tp;
    }
    int ex = (tid == 0) ? 0 : cur[tid - 1];
    oth[tid] = ex;
    __syncthreads();
    for (int jx = tid; jx < N_K; jx += 1024) {
        int key = (NBUCKET - 1) - min(out_len[jx], NBUCKET - 1);
        int pos = atomicAdd(&oth[key], 1);
        sorted_idx[pos] = jx;
    }
}

// ---------------- main kernel ------------------------------------------------
// block = 256 threads = 64 j-slots x 2 batches x 2 t-halves
// lane layout: h = tid&1, lb = (tid>>1)&1, jj = tid>>2 -> 16 consecutive
// sorted kernels per wave (similar out_len -> minimal loop-trip divergence).
//
// LDS: per batch, TWO parity-shifted copies of x packed as (c0,c1|c2,0) fp16
// u64 per position. copyE slot s = position s (s=0,1 and 1002,1003 are zero
// sentinels; data at s=2..1001). copyO slot m = copyE slot m+1. A 16B
// ds_read_b128 at even slot i yields positions (i, i+1):
//   q even -> copyE at slot q ; q odd -> copyO at slot q-1 (phys q+1003).
__global__ __launch_bounds__(256) void rocket_kernel(
    const float* __restrict__ x, const float* __restrict__ w,
    const float* __restrict__ bias, const int* __restrict__ dil,
    const int* __restrict__ start, const int* __restrict__ out_len,
    const int* __restrict__ pad_max_p, const int* __restrict__ sorted_idx,
    float* __restrict__ out) {
    __shared__ __align__(16) unsigned long long xs[NB * XSTR];

    const int tid = threadIdx.x;
    const int h  = tid & 1;
    const int lb = (tid >> 1) & (NB - 1);
    const int jj = tid >> 2;
    const int bg = blockIdx.x & 7;        // 8 batch groups of NB=2
    const int jg = blockIdx.x >> 3;

    // ---- stage x (NB batches) into LDS, both parity copies ------------------
    for (int lbb = 0; lbb < NB; ++lbb) {
        const float* xb = x + (size_t)(bg * NB + lbb) * (CIN * SEQ);
        unsigned long long* xe = xs + lbb * XSTR;
        for (int pos = tid; pos < SEQ; pos += 256) {
            float a0 = xb[pos];
            float a1 = xb[SEQ + pos];
            float a2 = xb[2 * SEQ + pos];
            unsigned u0 = (unsigned)__builtin_bit_cast(unsigned short, (_Float16)a0);
            unsigned u1 = (unsigned)__builtin_bit_cast(unsigned short, (_Float16)a1);
            unsigned u2 = (unsigned)__builtin_bit_cast(unsigned short, (_Float16)a2);
            unsigned long long v =
                (unsigned long long)(u0 | (u1 << 16)) | ((unsigned long long)u2 << 32);
            xe[2 + pos] = v;            // copyE: slot 2+pos = position pos
            xe[XSLOT + 1 + pos] = v;    // copyO: slot m = copyE slot m+1
        }
    }
    // zero sentinels: per batch E:{0,1,1002,1003} O:{0,1001,1002,1003}
    if (tid < NB * 8) {
        int lbb = tid >> 3, z = tid & 7;
        int off = (z < 2) ? z
                : (z < 4) ? (1000 + z)
                : (z == 4) ? XSLOT
                : (XSLOT + 996 + z);
        xs[lbb * XSTR + off] = 0ULL;
    }
    __syncthreads();

    const int ji = jg * NJJ + jj;
    if (ji >= N_K) return;
    const int j = sorted_idx[ji];

    const int d   = dil[j];
    const int ol  = out_len[j];
    const int off0 = start[j] - pad_max_p[0];   // = -pads[j]
    const float bj = bias[j];
    const float* wj = w + (size_t)j * (CIN * KM);

    float wf[CIN * KM];
#pragma unroll
    for (int i = 0; i < CIN * KM; ++i) wf[i] = wj[i];

    int ks = 1;
#pragma unroll
    for (int k = 1; k < KM; ++k)
        if (wf[k] != 0.f || wf[KM + k] != 0.f || wf[2 * KM + k] != 0.f) ks = k + 1;

    h2 wl[KM], wh[KM];
#pragma unroll
    for (int k = 0; k < KM; ++k) {
        h2 a, b;
        a.x = (_Float16)wf[k];        a.y = (_Float16)wf[KM + k];
        b.x = (_Float16)wf[2 * KM + k]; b.y = (_Float16)0.f;
        wl[k] = a; wh[k] = b;
    }

    const int half = (ol + 1) >> 1;
    const int t0 = h ? half : 0;
    const int t1 = h ? ol : half;

    int p[KM];
#pragma unroll
    for (int k = 0; k < KM; ++k) p[k] = 2 + off0 + min(k, ks - 1) * d + t0;

    const unsigned long long* xbase = xs + lb * XSTR;

    float mx = -3.4e38f;
    int cnt = 0;

#pragma unroll 2
    for (int t = t0; t < t1; t += 2) {
        float a00 = 0.f, a01 = 0.f, a10 = 0.f, a11 = 0.f;
#pragma unroll
        for (int k = 0; k < KM; ++k) {
            int q = min(max(p[k], 0), 1002);   // pair-base clamp, sentinels absorb OOB
            int i = q + (q & 1) * 1003;        // parity select: odd -> copyO (q-1 + XSLOT)
            uint4 v = *(const uint4*)(xbase + i);   // ds_read_b128: positions q, q+1
            a00 = __builtin_amdgcn_fdot2(__builtin_bit_cast(h2, v.x), wl[k], a00, false);
            a01 = __builtin_amdgcn_fdot2(__builtin_bit_cast(h2, v.y), wh[k], a01, false);
            a10 = __builtin_amdgcn_fdot2(__builtin_bit_cast(h2, v.z), wl[k], a10, false);
            a11 = __builtin_amdgcn_fdot2(__builtin_bit_cast(h2, v.w), wh[k], a11, false);
            p[k] += 2;
        }
        float v0 = a00 + a01 + bj;
        float v1 = a10 + a11 + bj;
        mx = fmaxf(mx, v0);
        cnt += (v0 > 0.f) ? 1 : 0;
        bool ok1 = (t + 1) < t1;
        mx = fmaxf(mx, ok1 ? v1 : -3.4e38f);
        cnt += (ok1 && v1 > 0.f) ? 1 : 0;
    }

    // combine the two t-halves (adjacent lanes)
    float mo = __shfl_xor(mx, 1);
    int   co = __shfl_xor(cnt, 1);
    mx = fmaxf(mx, mo);
    cnt += co;

    if (h == 0) {
        float2 r;
        r.x = mx;
        r.y = (float)cnt / (float)ol;
        *(float2*)(out + (size_t)(bg * NB + lb) * (2 * N_K) + 2 * j) = r;
    }
}

extern "C" void kernel_launch(void* const* d_in, const int* in_sizes, int n_in,
                              void* d_out, int out_size, void* d_ws, size_t ws_size,
                              hipStream_t stream) {
    const float* x       = (const float*)d_in[0];
    const float* weight  = (const float*)d_in[1];
    const float* bias    = (const float*)d_in[2];
    const int*   dil     = (const int*)d_in[3];
    const int*   start   = (const int*)d_in[4];
    const int*   out_len = (const int*)d_in[5];
    const int*   pad_max = (const int*)d_in[6];
    (void)in_sizes; (void)n_in; (void)out_size; (void)ws_size;

    int* sorted_idx = (int*)d_ws;  // 10000 ints

    sort_kernel<<<1, NBUCKET, 0, stream>>>(out_len, sorted_idx);

    const int jgroups = (N_K + NJJ - 1) / NJJ;  // 157
    rocket_kernel<<<jgroups * 8, 256, 0, stream>>>(
        x, weight, bias, dil, start, out_len, pad_max, sorted_idx, (float*)d_out);
}

// Round 3
// 346.975 us; speedup vs baseline: 1.3775x; 1.3775x over previous
//
#include <hip/hip_runtime.h>
#include <stdint.h>

#define N_K   10000
#define CIN   3
#define SEQ   1000
#define KM    11
#define NCLS  4096   // class buckets: (d-1)*4 + padflag*2 + padsize-bit
#define NSP   2048   // span (out_len) sort buckets
#define MAXQ  5632   // upper bound on quad count
#define QPB   8      // quads per block
#define NB    4      // batches per block

typedef _Float16 h2 __attribute__((ext_vector_type(2)));

// ---------------- prep: group j by (d, pad-class), form quads, sort by span --
__global__ __launch_bounds__(1024) void prep_kernel(
    const int* __restrict__ dil, const int* __restrict__ start,
    const int* __restrict__ out_len, const int* __restrict__ pad_max_p,
    int* __restrict__ sortedj, int2* __restrict__ quads) {
  __shared__ int cA[NCLS];
  __shared__ int cB[NCLS];
  __shared__ int cC[NSP];
  __shared__ int sh_total;
  const int tid = threadIdx.x;
  const int pm = pad_max_p[0];
  for (int i = tid; i < NCLS; i += 1024) cA[i] = 0;
  if (tid == 0) sh_total = 0;
  __syncthreads();
  // class histogram: all members of a class share d (exact); pad bits only
  // tighten span homogeneity (correctness never depends on bucketing).
  for (int j = tid; j < N_K; j += 1024) {
    int d = dil[j];
    int pads = pm - start[j];
    int kk = (d - 1) * 4 + (pads > 0 ? 2 : 0) + (2 * pads > 7 * d ? 1 : 0);
    kk = min(kk, NCLS - 1);
    atomicAdd(&cA[kk], 1);
  }
  __syncthreads();
  {  // inclusive scan of cA; 12 rounds (even) -> result lands back in cA
    int* cur = cA; int* oth = cB;
    for (int off = 1; off < NCLS; off <<= 1) {
      for (int i = tid; i < NCLS; i += 1024) {
        int v = cur[i];
        if (i >= off) v += cur[i - off];
        oth[i] = v;
      }
      __syncthreads();
      int* t = cur; cur = oth; oth = t;
    }
  }
  for (int i = tid; i < NCLS; i += 1024) cB[i] = i ? cA[i - 1] : 0;  // exclusive
  __syncthreads();
  for (int j = tid; j < N_K; j += 1024) {
    int d = dil[j];
    int pads = pm - start[j];
    int kk = (d - 1) * 4 + (pads > 0 ? 2 : 0) + (2 * pads > 7 * d ? 1 : 0);
    kk = min(kk, NCLS - 1);
    int pos = atomicAdd(&cB[kk], 1);
    sortedj[pos] = j;
  }
  __syncthreads();
  for (int i = tid; i < NSP; i += 1024) cC[i] = 0;
  __syncthreads();
  // phase A: per class, count quads into span bucket (rep member's out_len)
  for (int c = tid; c < NCLS; c += 1024) {
    int incl = cA[c];
    int n = incl - (c ? cA[c - 1] : 0);
    if (n <= 0) continue;
    int st = incl - n;
    int nq = (n + 3) >> 2;
    int espan = out_len[sortedj[st]];
    int sb = (NSP - 1) - min(espan, NSP - 1);   // descending span order
    atomicAdd(&cC[sb], nq);
    atomicAdd(&sh_total, nq);
  }
  __syncthreads();
  {  // inclusive scan of cC; 11 rounds (odd) -> result lands in cB
    int* cur = cC; int* oth = cB;
    for (int off = 1; off < NSP; off <<= 1) {
      for (int i = tid; i < NSP; i += 1024) {
        int v = cur[i];
        if (i >= off) v += cur[i - off];
        oth[i] = v;
      }
      __syncthreads();
      int* t = cur; cur = oth; oth = t;
    }
  }
  for (int i = tid; i < NSP; i += 1024) cC[i] = i ? cB[i - 1] : 0;  // exclusive
  __syncthreads();
  // placement: quad record = (first member offset in sortedj, last valid offset)
  for (int c = tid; c < NCLS; c += 1024) {
    int incl = cA[c];
    int n = incl - (c ? cA[c - 1] : 0);
    if (n <= 0) continue;
    int st = incl - n;
    int nq = (n + 3) >> 2;
    int espan = out_len[sortedj[st]];
    int sb = (NSP - 1) - min(espan, NSP - 1);
    int pos = atomicAdd(&cC[sb], nq);
    for (int q = 0; q < nq; ++q)
      quads[pos + q] = make_int2(st + 4 * q, st + n - 1);
  }
  __syncthreads();
  int total = sh_total;
  for (int i = total + tid; i < MAXQ; i += 1024) quads[i] = make_int2(-1, -1);
}

// ---------------- main kernel ------------------------------------------------
// block 256 = 8 quads x 4 batches x 8 tau-slices.
// Each thread computes 4 same-d kernels per x-tap read (DS traffic / 4).
__global__ __launch_bounds__(256) void rocket_kernel(
    const float* __restrict__ x, const float* __restrict__ w,
    const float* __restrict__ bias, const int* __restrict__ dil,
    const int* __restrict__ start, const int* __restrict__ out_len,
    const int* __restrict__ pad_max_p, const int* __restrict__ sortedj,
    const int2* __restrict__ quads, float* __restrict__ out) {
  __shared__ __align__(16) unsigned long long xs[NB * 1002];

  const int tid = threadIdx.x;
  const int h    = tid & 7;
  const int lb   = (tid >> 3) & 3;
  const int qloc = tid >> 5;
  const int bg = blockIdx.x & 3;
  const int qb = blockIdx.x >> 2;

  // stage x (4 batches) packed (c0,c1|c2,0) fp16 per position, zero sentinels
  for (int lbb = 0; lbb < NB; ++lbb) {
    const float* xb = x + (size_t)(bg * NB + lbb) * (CIN * SEQ);
    for (int pos = tid; pos < SEQ; pos += 256) {
      float a0 = xb[pos];
      float a1 = xb[SEQ + pos];
      float a2 = xb[2 * SEQ + pos];
      unsigned u0 = (unsigned)__builtin_bit_cast(unsigned short, (_Float16)a0);
      unsigned u1 = (unsigned)__builtin_bit_cast(unsigned short, (_Float16)a1);
      unsigned u2 = (unsigned)__builtin_bit_cast(unsigned short, (_Float16)a2);
      xs[lbb * 1002 + 1 + pos] =
          (unsigned long long)(u0 | (u1 << 16)) | ((unsigned long long)u2 << 32);
    }
  }
  if (tid < NB * 2) xs[(tid >> 1) * 1002 + (tid & 1) * 1001] = 0ULL;
  __syncthreads();

  int2 qr = quads[qb * QPB + qloc];
  if (qr.x < 0) return;

  int jm[4];
#pragma unroll
  for (int i = 0; i < 4; ++i) jm[i] = sortedj[min(qr.x + i, qr.y)];

  const int pm = pad_max_p[0];
  const int d = dil[jm[0]];  // class key guarantees same d for all members

  int sm[4], olm[4];
  float bb[4];
  int tlo = 0x7fffffff, thi = 0;
#pragma unroll
  for (int m = 0; m < 4; ++m) {
    sm[m] = start[jm[m]];
    olm[m] = out_len[jm[m]];
    bb[m] = bias[jm[m]];
    tlo = min(tlo, sm[m]);
    thi = max(thi, sm[m] + olm[m]);
  }

  h2 wl[4][KM];   // (w_c0, w_c1) per member per tap
  h2 wh2[2][KM];  // (w_c2 of member 2p, w_c2 of member 2p+1)
#pragma unroll
  for (int m = 0; m < 4; ++m) {
    const float* wj = w + (size_t)jm[m] * (CIN * KM);
#pragma unroll
    for (int k = 0; k < KM; ++k) {
      h2 a;
      a.x = (_Float16)wj[k];
      a.y = (_Float16)wj[KM + k];
      wl[m][k] = a;
    }
  }
#pragma unroll
  for (int pp = 0; pp < 2; ++pp) {
    const float* w0 = w + (size_t)jm[2 * pp] * (CIN * KM) + 2 * KM;
    const float* w1 = w + (size_t)jm[2 * pp + 1] * (CIN * KM) + 2 * KM;
#pragma unroll
    for (int k = 0; k < KM; ++k) {
      h2 a;
      a.x = (_Float16)w0[k];
      a.y = (_Float16)w1[k];
      wh2[pp][k] = a;
    }
  }

  const int len = thi - tlo;
  const int ta = tlo + ((len * h) >> 3);
  const int tb = tlo + ((len * (h + 1)) >> 3);
  const int lbase = lb * 1002;
  const int clo = lbase, chi = lbase + 1001;

  int p[KM];
#pragma unroll
  for (int k = 0; k < KM; ++k) p[k] = lbase + 1 + (ta - pm) + k * d;

  float mx[4] = {-3.0e38f, -3.0e38f, -3.0e38f, -3.0e38f};
  int cnt[4] = {0, 0, 0, 0};

  for (int t = ta; t < tb; ++t) {
    float a0[4] = {0.f, 0.f, 0.f, 0.f};
    float a1[4] = {0.f, 0.f, 0.f, 0.f};
#pragma unroll
    for (int k = 0; k < KM; ++k) {
      int q = min(max(p[k], clo), chi);       // v_med3, sentinels absorb OOB
      unsigned long long v = xs[q];           // ds_read_b64, shared by 4 j
      unsigned lo32 = (unsigned)v;
      unsigned hi32 = (unsigned)(v >> 32);
      h2 xl = __builtin_bit_cast(h2, lo32);          // (c0, c1)
      h2 xhl = __builtin_bit_cast(h2, hi32);         // (c2, 0)
      h2 xhh = __builtin_bit_cast(h2, hi32 << 16);   // (0, c2)
      a0[0] = __builtin_amdgcn_fdot2(xl, wl[0][k], a0[0], false);
      a0[1] = __builtin_amdgcn_fdot2(xl, wl[1][k], a0[1], false);
      a0[2] = __builtin_amdgcn_fdot2(xl, wl[2][k], a0[2], false);
      a0[3] = __builtin_amdgcn_fdot2(xl, wl[3][k], a0[3], false);
      a1[0] = __builtin_amdgcn_fdot2(xhl, wh2[0][k], a1[0], false);
      a1[1] = __builtin_amdgcn_fdot2(xhh, wh2[0][k], a1[1], false);
      a1[2] = __builtin_amdgcn_fdot2(xhl, wh2[1][k], a1[2], false);
      a1[3] = __builtin_amdgcn_fdot2(xhh, wh2[1][k], a1[3], false);
      p[k]++;
    }
#pragma unroll
    for (int m = 0; m < 4; ++m) {
      float val = a0[m] + a1[m] + bb[m];
      bool in = (unsigned)(t - sm[m]) < (unsigned)olm[m];
      mx[m] = fmaxf(mx[m], in ? val : -3.0e38f);
      cnt[m] += (in && val > 0.f) ? 1 : 0;
    }
  }

  // reduce across the 8 tau-slices (lanes differing in bits 0..2)
#pragma unroll
  for (int m = 0; m < 4; ++m) {
#pragma unroll
    for (int off = 1; off < 8; off <<= 1) {
      mx[m] = fmaxf(mx[m], __shfl_xor(mx[m], off));
      cnt[m] += __shfl_xor(cnt[m], off);
    }
  }

  if (h == 0) {
    const int b = bg * NB + lb;
#pragma unroll
    for (int m = 0; m < 4; ++m) {
      float2 r;
      r.x = mx[m];
      r.y = (float)cnt[m] / (float)olm[m];
      *(float2*)(out + (size_t)b * (2 * N_K) + 2 * jm[m]) = r;
    }
  }
}

extern "C" void kernel_launch(void* const* d_in, const int* in_sizes, int n_in,
                              void* d_out, int out_size, void* d_ws, size_t ws_size,
                              hipStream_t stream) {
  const float* x       = (const float*)d_in[0];
  const float* weight  = (const float*)d_in[1];
  const float* bias    = (const float*)d_in[2];
  const int*   dil     = (const int*)d_in[3];
  const int*   start   = (const int*)d_in[4];
  const int*   out_len = (const int*)d_in[5];
  const int*   pad_max = (const int*)d_in[6];
  (void)in_sizes; (void)n_in; (void)out_size; (void)ws_size;

  int2* quads   = (int2*)d_ws;                          // MAXQ int2
  int*  sortedj = (int*)((char*)d_ws + MAXQ * sizeof(int2));  // N_K ints

  prep_kernel<<<1, 1024, 0, stream>>>(dil, start, out_len, pad_max,
                                      sortedj, quads);

  rocket_kernel<<<(MAXQ / QPB) * 4, 256, 0, stream>>>(
      x, weight, bias, dil, start, out_len, pad_max, sortedj, quads,
      (float*)d_out);
}